// Round 4
// baseline (309.865 us; speedup 1.0000x reference)
//
#include <hip/hip_runtime.h>
#include <math.h>

#define DM 512          // d_model
#define NQ 16           // num output queries
#define NG (NQ + 1)     // 16 score rows + 1 pooled-v row

typedef __attribute__((ext_vector_type(2))) float f32x2;

__device__ __forceinline__ float wave_reduce_sum(float v) {
    #pragma unroll
    for (int off = 32; off > 0; off >>= 1) v += __shfl_xor(v, off, 64);
    return v;
}
__device__ __forceinline__ float wave_reduce_max(float v) {
    #pragma unroll
    for (int off = 32; off > 0; off >>= 1) v = fmaxf(v, __shfl_xor(v, off, 64));
    return v;
}

// --- K1: fused independent precompute --------------------------------------
// blocks 0..127   : PET[d][n] generation (8 n-tiles x 16 j-groups)
// blocks 128..255 : LDS-tiled transpose Wk->WkT, Wv->WvT
// block  256      : LayerNorm of query*scale (4 waves x 4 rows)
__global__ void k1_setup(const float* __restrict__ Wk, const float* __restrict__ Wv,
                         const float* __restrict__ query,
                         const float* __restrict__ ln_q_w, const float* __restrict__ ln_q_b,
                         float* __restrict__ PET, float* __restrict__ WkT,
                         float* __restrict__ WvT, float* __restrict__ q_ln, int N) {
    __shared__ float tile[64][65];
    int bx = blockIdx.x;
    int lane = threadIdx.x & 63;
    int w = threadIdx.x >> 6;

    if (bx < 128) {                       // --- PET ---
        int ntile = bx & 7, jg = bx >> 3;
        int n = ntile * 64 + lane;
        float p = (float)(N - 1 - n);     // reversed PE
        const float c = -logf(10000.f) / (float)DM;
        int jbase = jg * 16 + w * 4;
        #pragma unroll
        for (int u = 0; u < 4; ++u) {
            int j = jbase + u;
            float wj = expf((float)(2 * j) * c);
            float ang = p * wj;
            PET[(size_t)(2 * j) * N + n] = sinf(ang);
            PET[(size_t)(2 * j + 1) * N + n] = cosf(ang);
        }
    } else if (bx < 256) {                // --- transpose ---
        int t = bx - 128;
        const float* W = (t >> 6) ? Wv : Wk;
        float* WT = (t >> 6) ? WvT : WkT;
        int tl = t & 63;
        int te = tl >> 3, td = tl & 7;    // 8x8 tiles of 64x64
        #pragma unroll
        for (int i = 0; i < 16; ++i) {
            int el = w * 16 + i;
            tile[el][lane] = W[(size_t)(te * 64 + el) * DM + td * 64 + lane];
        }
        __syncthreads();
        #pragma unroll
        for (int i = 0; i < 16; ++i) {
            int dl = w * 16 + i;
            WT[(size_t)(td * 64 + dl) * DM + te * 64 + lane] = tile[lane][dl];
        }
    } else {                              // --- query LN ---
        const float scale = 22.627416997969522f;   // sqrt(512)
        for (int qi = 0; qi < 4; ++qi) {
            int q = w * 4 + qi;
            float vals[8], s = 0.f, s2 = 0.f;
            #pragma unroll
            for (int i = 0; i < 8; ++i) {
                float x = query[q * DM + i * 64 + lane] * scale;
                vals[i] = x; s += x; s2 += x * x;
            }
            s = wave_reduce_sum(s); s2 = wave_reduce_sum(s2);
            float m = s * (1.f / DM);
            float var = s2 * (1.f / DM) - m * m;
            float rstd = rsqrtf(var + 1e-5f);
            #pragma unroll
            for (int i = 0; i < 8; ++i) {
                int d = i * 64 + lane;
                q_ln[q * DM + d] = (vals[i] - m) * rstd * ln_q_w[d] + ln_q_b[d];
            }
        }
    }
}

// --- K2: qh[q][e] = q_ln[q] . Wq[e] + bq[e], one wave per output -----------
__global__ void k2_qh(const float* __restrict__ q_ln, const float* __restrict__ Wq,
                      const float* __restrict__ bq, float* __restrict__ qh) {
    int idx = blockIdx.x * 4 + (threadIdx.x >> 6);   // 0..8191
    int lane = threadIdx.x & 63;
    int q = idx >> 9, e = idx & 511;
    const float4* wr = (const float4*)(Wq + (size_t)e * DM);
    const float4* xr = (const float4*)(q_ln + (size_t)q * DM);
    float4 w0 = wr[lane * 2], w1 = wr[lane * 2 + 1];
    float4 x0 = xr[lane * 2], x1 = xr[lane * 2 + 1];
    float s = w0.x * x0.x + w0.y * x0.y + w0.z * x0.z + w0.w * x0.w
            + w1.x * x1.x + w1.y * x1.y + w1.z * x1.z + w1.w * x1.w;
    s = wave_reduce_sum(s);
    if (lane == 0) qh[q * DM + e] = s + bq[e];
}

// --- K3: qt[g][d] (g<16) and wv[d] (g=16) via contiguous WkT/WvT rows ------
//         A[g][d] = coeff * ln_lat_w[d]; A2 = duplicated pair for pk_fma ----
__global__ void k3_qt(const float* __restrict__ qh, const float* __restrict__ WkT,
                      const float* __restrict__ Wo, const float* __restrict__ WvT,
                      const float* __restrict__ lnw,
                      float* __restrict__ qt, float* __restrict__ A,
                      f32x2* __restrict__ A2, float* __restrict__ wvout) {
    int idx = blockIdx.x * 4 + (threadIdx.x >> 6);   // 0..8703
    int lane = threadIdx.x & 63;
    int g = idx >> 9, d = idx & 511;
    const float4* wr;
    const float4* xr;
    if (g < NQ) {
        wr = (const float4*)(WkT + (size_t)d * DM);
        xr = (const float4*)(qh + (size_t)g * DM);
    } else {
        wr = (const float4*)(WvT + (size_t)d * DM);
        xr = (const float4*)Wo;
    }
    float4 w0 = wr[lane * 2], w1 = wr[lane * 2 + 1];
    float4 x0 = xr[lane * 2], x1 = xr[lane * 2 + 1];
    float s = w0.x * x0.x + w0.y * x0.y + w0.z * x0.z + w0.w * x0.w
            + w1.x * x1.x + w1.y * x1.y + w1.z * x1.z + w1.w * x1.w;
    s = wave_reduce_sum(s);
    if (lane == 0) {
        if (g < NQ) qt[g * DM + d] = s;
        else wvout[d] = s;
        float a = s * lnw[d];
        A[g * DM + d] = a;
        f32x2 ap; ap.x = a; ap.y = a;
        A2[g * DM + d] = ap;
    }
}

// --- K4: peA rows (g<17), peS (g=17), peQ (g=18) + consts wave-tasks -------
__global__ void k4_pea(const float* __restrict__ A, const float* __restrict__ PET,
                       const float* __restrict__ qt, const float* __restrict__ qh,
                       const float* __restrict__ wv, const float* __restrict__ lnb,
                       const float* __restrict__ bk, const float* __restrict__ Wo,
                       const float* __restrict__ bv,
                       float* __restrict__ peA, float* __restrict__ peS,
                       float* __restrict__ peQ, float* __restrict__ consts, int N) {
    __shared__ float red[4][64];
    int bx = blockIdx.x;
    int lane = threadIdx.x & 63;
    int w = threadIdx.x >> 6;

    if (bx < 152) {
        int g = bx >> 3, ntile = bx & 7;
        int n = ntile * 64 + lane;
        int d0 = w * 128;
        float acc = 0.f;
        if (g < NG) {
            for (int i = 0; i < 128; ++i) {
                int d = d0 + i;
                acc = fmaf(A[(size_t)g * DM + d], PET[(size_t)d * N + n], acc);
            }
        } else if (g == NG) {
            for (int i = 0; i < 128; ++i) acc += PET[(size_t)(d0 + i) * N + n];
        } else {
            for (int i = 0; i < 128; ++i) {
                float v = PET[(size_t)(d0 + i) * N + n];
                acc = fmaf(v, v, acc);
            }
        }
        red[w][lane] = acc;
        __syncthreads();
        if (w != 0) return;
        float tot = red[0][lane] + red[1][lane] + red[2][lane] + red[3][lane];
        if (g < NG) peA[(size_t)g * N + n] = tot;
        else if (g == NG) peS[n] = tot;
        else peQ[n] = tot;
    } else {
        int t = (bx - 152) * 4 + w;       // 0..19, valid 0..16
        if (t > NQ) return;
        if (t < NQ) {
            float sa = 0.f, sc = 0.f, qb = 0.f;
            #pragma unroll
            for (int i = 0; i < 8; ++i) {
                int d = i * 64 + lane;
                sa += A[t * DM + d];
                sc = fmaf(qt[t * DM + d], lnb[d], sc);
                qb = fmaf(qh[t * DM + d], bk[d], qb);
            }
            sa = wave_reduce_sum(sa);
            sc = wave_reduce_sum(sc);
            qb = wave_reduce_sum(qb);
            if (lane == 0) { consts[t] = sa; consts[16 + t] = sc + qb; }
        } else {
            float sa = 0.f, cv = 0.f, bvo = 0.f;
            #pragma unroll
            for (int i = 0; i < 8; ++i) {
                int d = i * 64 + lane;
                sa += A[NQ * DM + d];
                cv = fmaf(wv[d], lnb[d], cv);
                bvo = fmaf(Wo[d], bv[d], bvo);
            }
            sa = wave_reduce_sum(sa);
            cv = wave_reduce_sum(cv);
            bvo = wave_reduce_sum(bvo);
            if (lane == 0) { consts[32] = sa; consts[33] = cv + bvo; }
        }
    }
}

// --- K5: main. lane = 2 columns (float2 loads), 4 waves split d. -----------
// 17 acc rows via v_pk_fma_f32 (sgpr-pair broadcast of duplicated A2).
__launch_bounds__(256, 4)
__global__ void main_kernel(const float* __restrict__ latents,
                            const float* __restrict__ PET,
                            const unsigned long long* __restrict__ A2,
                            const float* __restrict__ peA,
                            const float* __restrict__ peS,
                            const float* __restrict__ peQ,
                            const float* __restrict__ consts,
                            float* __restrict__ scores,
                            float* __restrict__ vbuf, int N) {
    int b = blockIdx.y;
    int lane = threadIdx.x & 63;
    int w = threadIdx.x >> 6;
    int n0 = blockIdx.x * 128 + lane * 2;
    const float scale = 22.627416997969522f;    // sqrt(512)

    int d0 = __builtin_amdgcn_readfirstlane(w * 128);   // wave-uniform
    const float* latf = latents + (size_t)b * DM * N + (size_t)d0 * N + n0;
    const float* petf = PET + (size_t)d0 * N + n0;

    f32x2 acc[NG];
    #pragma unroll
    for (int i = 0; i < NG; ++i) { acc[i].x = 0.f; acc[i].y = 0.f; }
    f32x2 S1 = {0.f, 0.f}, S2 = {0.f, 0.f}, Sx = {0.f, 0.f};

    const int U = 4;                 // chunk size (d per chunk)
    const int NC = 128 / U;          // 32 chunks
    f32x2 xb[2][U], pb[2][U];
    #pragma unroll
    for (int u = 0; u < U; ++u) {
        xb[0][u] = __builtin_nontemporal_load((const f32x2*)(latf + (size_t)u * N));
        pb[0][u] = *(const f32x2*)(petf + (size_t)u * N);
    }
    int cur = 0;
    for (int c = 0; c < NC; ++c) {
        int nxt = cur ^ 1;
        if (c + 1 < NC) {
            #pragma unroll
            for (int u = 0; u < U; ++u) {
                size_t dd = (size_t)((c + 1) * U + u) * N;
                xb[nxt][u] = __builtin_nontemporal_load((const f32x2*)(latf + dd));
                pb[nxt][u] = *(const f32x2*)(petf + dd);
            }
        }
        #pragma unroll
        for (int u = 0; u < U; ++u) {
            f32x2 x = xb[cur][u], pe = pb[cur][u];
            S1 += x;
            S2.x = fmaf(x.x, x.x, S2.x); S2.y = fmaf(x.y, x.y, S2.y);
            Sx.x = fmaf(x.x, pe.x, Sx.x); Sx.y = fmaf(x.y, pe.y, Sx.y);
            int d = d0 + c * U + u;              // wave-uniform index
            #pragma unroll
            for (int q = 0; q < NG; ++q) {
                unsigned long long a = A2[(size_t)q * DM + d];  // s_load pair
                asm("v_pk_fma_f32 %0, %1, %2, %0"
                    : "+v"(acc[q]) : "s"(a), "v"(x));
            }
        }
        cur = nxt;
    }

    __shared__ f32x2 red[4][NG + 3][64];
    red[w][0][lane] = S1;
    red[w][1][lane] = S2;
    red[w][2][lane] = Sx;
    #pragma unroll
    for (int i = 0; i < NG; ++i) red[w][3 + i][lane] = acc[i];
    __syncthreads();
    if (w != 0) return;

    f32x2 tot[NG + 3];
    #pragma unroll
    for (int i = 0; i < NG + 3; ++i)
        tot[i] = red[0][i][lane] + red[1][i][lane] + red[2][i][lane] + red[3][i][lane];

    f32x2 peS2 = *(const f32x2*)(peS + n0);
    f32x2 peQ2 = *(const f32x2*)(peQ + n0);
    f32x2 m = (scale * tot[0] + peS2) * (1.f / DM);
    f32x2 ex2 = (scale * scale * tot[1] + 2.f * scale * tot[2] + peQ2) * (1.f / DM);
    f32x2 rstd;
    rstd.x = rsqrtf(ex2.x - m.x * m.x + 1e-5f);
    rstd.y = rsqrtf(ex2.y - m.y * m.y + 1e-5f);

    float sumAv = consts[32], CvT = consts[33];
    f32x2 peAv = *(const f32x2*)(peA + (size_t)NQ * N + n0);
    f32x2 v = rstd * (scale * tot[3 + NQ] + peAv - m * sumAv) + CvT;
    *(f32x2*)(vbuf + (size_t)b * N + n0) = v;

    const float isd = 0.044194173824159216f;    // 1/sqrt(512)
    #pragma unroll
    for (int q = 0; q < NQ; ++q) {
        f32x2 peAq = *(const f32x2*)(peA + (size_t)q * N + n0);
        f32x2 sc = (rstd * (scale * tot[3 + q] + peAq - m * consts[q])
                    + consts[16 + q]) * isd;
        *(f32x2*)(scores + ((size_t)b * NQ + q) * N + n0) = sc;
    }
}

// --- K6: softmax, 4 rows per block (wave per row), float4 IO ---------------
__global__ void softmax_kernel(const float* __restrict__ scores,
                               const float* __restrict__ vbuf,
                               const float* __restrict__ query_mask,
                               const float* __restrict__ bo,
                               float* __restrict__ out_logits,
                               float* __restrict__ out_attn, int N) {
    int r = blockIdx.x * 4 + (threadIdx.x >> 6);   // b*NQ + q
    int b = r >> 4;
    int lane = threadIdx.x & 63;
    float4* attn_row = (float4*)(out_attn + (size_t)r * N);
    float qm = query_mask[r];
    int nv = N / 4;                     // float4 count per row
    if (qm == 0.f) {                    // fully masked row: uniform weights, wiped logits
        float u = 1.f / (float)N;
        float4 uv = make_float4(u, u, u, u);
        for (int i = lane; i < nv; i += 64) attn_row[i] = uv;
        if (lane == 0) out_logits[r] = bo[0];
        return;
    }
    const float4* srow = (const float4*)(scores + (size_t)r * N);
    float4 sv[2];
    sv[0] = srow[lane]; sv[1] = srow[64 + lane];
    float mx = fmaxf(fmaxf(fmaxf(sv[0].x, sv[0].y), fmaxf(sv[0].z, sv[0].w)),
                     fmaxf(fmaxf(sv[1].x, sv[1].y), fmaxf(sv[1].z, sv[1].w)));
    mx = wave_reduce_max(mx);
    float sum = 0.f;
    #pragma unroll
    for (int i = 0; i < 2; ++i) {
        sv[i].x = expf(sv[i].x - mx); sv[i].y = expf(sv[i].y - mx);
        sv[i].z = expf(sv[i].z - mx); sv[i].w = expf(sv[i].w - mx);
        sum += sv[i].x + sv[i].y + sv[i].z + sv[i].w;
    }
    sum = wave_reduce_sum(sum);
    float inv = 1.f / sum;
    const float4* vrow = (const float4*)(vbuf + (size_t)b * N);
    float lp = 0.f;
    #pragma unroll
    for (int i = 0; i < 2; ++i) {
        float4 vv = vrow[i * 64 + lane];
        float4 wgt;
        wgt.x = sv[i].x * inv; wgt.y = sv[i].y * inv;
        wgt.z = sv[i].z * inv; wgt.w = sv[i].w * inv;
        attn_row[i * 64 + lane] = wgt;
        lp += wgt.x * vv.x + wgt.y * vv.y + wgt.z * vv.z + wgt.w * vv.w;
    }
    lp = wave_reduce_sum(lp);
    if (lane == 0) out_logits[r] = lp + bo[0];
}

extern "C" void kernel_launch(void* const* d_in, const int* in_sizes, int n_in,
                              void* d_out, int out_size, void* d_ws, size_t ws_size,
                              hipStream_t stream) {
    const float* latents    = (const float*)d_in[0];
    const float* query_mask = (const float*)d_in[1];
    const float* query      = (const float*)d_in[2];
    const float* ln_lat_w   = (const float*)d_in[3];
    const float* ln_lat_b   = (const float*)d_in[4];
    const float* ln_q_w     = (const float*)d_in[5];
    const float* ln_q_b     = (const float*)d_in[6];
    const float* Wq         = (const float*)d_in[7];
    const float* bq         = (const float*)d_in[8];
    const float* Wk         = (const float*)d_in[9];
    const float* bk         = (const float*)d_in[10];
    const float* Wv         = (const float*)d_in[11];
    const float* bv         = (const float*)d_in[12];
    const float* Wo         = (const float*)d_in[13];
    const float* bo         = (const float*)d_in[14];

    int B = in_sizes[1] / NQ;
    int N = in_sizes[0] / (DM * B);

    float* ws = (float*)d_ws;
    size_t off = 0;
    float* PET    = ws + off; off += (size_t)DM * N;
    float* WkT    = ws + off; off += (size_t)DM * DM;
    float* WvT    = ws + off; off += (size_t)DM * DM;
    float* peS    = ws + off; off += N;
    float* peQ    = ws + off; off += N;
    float* q_ln   = ws + off; off += NQ * DM;
    float* qh     = ws + off; off += NQ * DM;
    float* qt     = ws + off; off += NQ * DM;
    float* A      = ws + off; off += NG * DM;
    float* A2     = ws + off; off += (size_t)NG * DM * 2;
    float* wv     = ws + off; off += DM;
    float* peA    = ws + off; off += (size_t)NG * N;
    float* consts = ws + off; off += 64;
    float* scores = ws + off; off += (size_t)B * NQ * N;
    float* vbuf   = ws + off; off += (size_t)B * N;

    float* out_logits = (float*)d_out;
    float* out_attn   = out_logits + (size_t)B * NQ;

    k1_setup<<<257, 256, 0, stream>>>(Wk, Wv, query, ln_q_w, ln_q_b,
                                      PET, WkT, WvT, q_ln, N);
    k2_qh<<<NQ * DM / 4, 256, 0, stream>>>(q_ln, Wq, bq, qh);
    k3_qt<<<NG * DM / 4, 256, 0, stream>>>(qh, WkT, Wo, WvT, ln_lat_w,
                                           qt, A, (f32x2*)A2, wv);
    k4_pea<<<157, 256, 0, stream>>>(A, PET, qt, qh, wv, ln_lat_b, bk, Wo, bv,
                                    peA, peS, peQ, consts, N);
    dim3 gmain(N / 128, B);
    main_kernel<<<gmain, 256, 0, stream>>>(latents, PET,
                                           (const unsigned long long*)A2,
                                           peA, peS, peQ, consts,
                                           scores, vbuf, N);
    softmax_kernel<<<B * NQ / 4, 256, 0, stream>>>(scores, vbuf, query_mask, bo,
                                                   out_logits, out_attn, N);
}

// Round 5
// 296.124 us; speedup vs baseline: 1.0464x; 1.0464x over previous
//
#include <hip/hip_runtime.h>
#include <math.h>

#define DM 512          // d_model
#define NQ 16           // num output queries
#define NG (NQ + 1)     // 16 score rows + 1 pooled-v row

__device__ __forceinline__ float wave_reduce_sum(float v) {
    #pragma unroll
    for (int off = 32; off > 0; off >>= 1) v += __shfl_xor(v, off, 64);
    return v;
}
__device__ __forceinline__ float wave_reduce_max(float v) {
    #pragma unroll
    for (int off = 32; off > 0; off >>= 1) v = fmaxf(v, __shfl_xor(v, off, 64));
    return v;
}

// --- K1: fused independent precompute --------------------------------------
// blocks 0..127   : PET[d][n] generation (8 n-tiles x 16 j-groups)
// blocks 128..255 : LDS-tiled transpose Wk->WkT, Wv->WvT
// block  256      : LayerNorm of query*scale (4 waves x 4 rows)
__global__ void k1_setup(const float* __restrict__ Wk, const float* __restrict__ Wv,
                         const float* __restrict__ query,
                         const float* __restrict__ ln_q_w, const float* __restrict__ ln_q_b,
                         float* __restrict__ PET, float* __restrict__ WkT,
                         float* __restrict__ WvT, float* __restrict__ q_ln, int N) {
    __shared__ float tile[64][65];
    int bx = blockIdx.x;
    int lane = threadIdx.x & 63;
    int w = threadIdx.x >> 6;

    if (bx < 128) {                       // --- PET ---
        int ntile = bx & 7, jg = bx >> 3;
        int n = ntile * 64 + lane;
        float p = (float)(N - 1 - n);     // reversed PE
        const float c = -logf(10000.f) / (float)DM;
        int jbase = jg * 16 + w * 4;
        #pragma unroll
        for (int u = 0; u < 4; ++u) {
            int j = jbase + u;
            float wj = expf((float)(2 * j) * c);
            float ang = p * wj;
            PET[(size_t)(2 * j) * N + n] = sinf(ang);
            PET[(size_t)(2 * j + 1) * N + n] = cosf(ang);
        }
    } else if (bx < 256) {                // --- transpose ---
        int t = bx - 128;
        const float* W = (t >> 6) ? Wv : Wk;
        float* WT = (t >> 6) ? WvT : WkT;
        int tl = t & 63;
        int te = tl >> 3, td = tl & 7;    // 8x8 tiles of 64x64
        #pragma unroll
        for (int i = 0; i < 16; ++i) {
            int el = w * 16 + i;
            tile[el][lane] = W[(size_t)(te * 64 + el) * DM + td * 64 + lane];
        }
        __syncthreads();
        #pragma unroll
        for (int i = 0; i < 16; ++i) {
            int dl = w * 16 + i;
            WT[(size_t)(td * 64 + dl) * DM + te * 64 + lane] = tile[lane][dl];
        }
    } else {                              // --- query LN ---
        const float scale = 22.627416997969522f;   // sqrt(512)
        for (int qi = 0; qi < 4; ++qi) {
            int q = w * 4 + qi;
            float vals[8], s = 0.f, s2 = 0.f;
            #pragma unroll
            for (int i = 0; i < 8; ++i) {
                float x = query[q * DM + i * 64 + lane] * scale;
                vals[i] = x; s += x; s2 += x * x;
            }
            s = wave_reduce_sum(s); s2 = wave_reduce_sum(s2);
            float m = s * (1.f / DM);
            float var = s2 * (1.f / DM) - m * m;
            float rstd = rsqrtf(var + 1e-5f);
            #pragma unroll
            for (int i = 0; i < 8; ++i) {
                int d = i * 64 + lane;
                q_ln[q * DM + d] = (vals[i] - m) * rstd * ln_q_w[d] + ln_q_b[d];
            }
        }
    }
}

// --- K2: qh[q][e] = q_ln[q] . Wq[e] + bq[e], one wave per output -----------
__global__ void k2_qh(const float* __restrict__ q_ln, const float* __restrict__ Wq,
                      const float* __restrict__ bq, float* __restrict__ qh) {
    int idx = blockIdx.x * 4 + (threadIdx.x >> 6);   // 0..8191
    int lane = threadIdx.x & 63;
    int q = idx >> 9, e = idx & 511;
    const float4* wr = (const float4*)(Wq + (size_t)e * DM);
    const float4* xr = (const float4*)(q_ln + (size_t)q * DM);
    float4 w0 = wr[lane * 2], w1 = wr[lane * 2 + 1];
    float4 x0 = xr[lane * 2], x1 = xr[lane * 2 + 1];
    float s = w0.x * x0.x + w0.y * x0.y + w0.z * x0.z + w0.w * x0.w
            + w1.x * x1.x + w1.y * x1.y + w1.z * x1.z + w1.w * x1.w;
    s = wave_reduce_sum(s);
    if (lane == 0) qh[q * DM + e] = s + bq[e];
}

// --- K3: qt[g][d] (g<16) and wv[d] (g=16) via contiguous WkT/WvT rows ------
//         A[g][d] = coeff * ln_lat_w[d]
__global__ void k3_qt(const float* __restrict__ qh, const float* __restrict__ WkT,
                      const float* __restrict__ Wo, const float* __restrict__ WvT,
                      const float* __restrict__ lnw,
                      float* __restrict__ qt, float* __restrict__ A,
                      float* __restrict__ wvout) {
    int idx = blockIdx.x * 4 + (threadIdx.x >> 6);   // 0..8703
    int lane = threadIdx.x & 63;
    int g = idx >> 9, d = idx & 511;
    const float4* wr;
    const float4* xr;
    if (g < NQ) {
        wr = (const float4*)(WkT + (size_t)d * DM);
        xr = (const float4*)(qh + (size_t)g * DM);
    } else {
        wr = (const float4*)(WvT + (size_t)d * DM);
        xr = (const float4*)Wo;
    }
    float4 w0 = wr[lane * 2], w1 = wr[lane * 2 + 1];
    float4 x0 = xr[lane * 2], x1 = xr[lane * 2 + 1];
    float s = w0.x * x0.x + w0.y * x0.y + w0.z * x0.z + w0.w * x0.w
            + w1.x * x1.x + w1.y * x1.y + w1.z * x1.z + w1.w * x1.w;
    s = wave_reduce_sum(s);
    if (lane == 0) {
        if (g < NQ) qt[g * DM + d] = s;
        else wvout[d] = s;
        A[g * DM + d] = s * lnw[d];
    }
}

// --- K4: peA rows (g<17), peS (g=17), peQ (g=18) + consts wave-tasks -------
__global__ void k4_pea(const float* __restrict__ A, const float* __restrict__ PET,
                       const float* __restrict__ qt, const float* __restrict__ qh,
                       const float* __restrict__ wv, const float* __restrict__ lnb,
                       const float* __restrict__ bk, const float* __restrict__ Wo,
                       const float* __restrict__ bv,
                       float* __restrict__ peA, float* __restrict__ peS,
                       float* __restrict__ peQ, float* __restrict__ consts, int N) {
    __shared__ float red[4][64];
    int bx = blockIdx.x;
    int lane = threadIdx.x & 63;
    int w = threadIdx.x >> 6;

    if (bx < 152) {
        int g = bx >> 3, ntile = bx & 7;
        int n = ntile * 64 + lane;
        int d0 = w * 128;
        float acc = 0.f;
        if (g < NG) {
            for (int i = 0; i < 128; ++i) {
                int d = d0 + i;
                acc = fmaf(A[(size_t)g * DM + d], PET[(size_t)d * N + n], acc);
            }
        } else if (g == NG) {
            for (int i = 0; i < 128; ++i) acc += PET[(size_t)(d0 + i) * N + n];
        } else {
            for (int i = 0; i < 128; ++i) {
                float v = PET[(size_t)(d0 + i) * N + n];
                acc = fmaf(v, v, acc);
            }
        }
        red[w][lane] = acc;
        __syncthreads();
        if (w != 0) return;
        float tot = red[0][lane] + red[1][lane] + red[2][lane] + red[3][lane];
        if (g < NG) peA[(size_t)g * N + n] = tot;
        else if (g == NG) peS[n] = tot;
        else peQ[n] = tot;
    } else {
        int t = (bx - 152) * 4 + w;       // 0..19, valid 0..16
        if (t > NQ) return;
        if (t < NQ) {
            float sa = 0.f, sc = 0.f, qb = 0.f;
            #pragma unroll
            for (int i = 0; i < 8; ++i) {
                int d = i * 64 + lane;
                sa += A[t * DM + d];
                sc = fmaf(qt[t * DM + d], lnb[d], sc);
                qb = fmaf(qh[t * DM + d], bk[d], qb);
            }
            sa = wave_reduce_sum(sa);
            sc = wave_reduce_sum(sc);
            qb = wave_reduce_sum(qb);
            if (lane == 0) { consts[t] = sa; consts[16 + t] = sc + qb; }
        } else {
            float sa = 0.f, cv = 0.f, bvo = 0.f;
            #pragma unroll
            for (int i = 0; i < 8; ++i) {
                int d = i * 64 + lane;
                sa += A[NQ * DM + d];
                cv = fmaf(wv[d], lnb[d], cv);
                bvo = fmaf(Wo[d], bv[d], bvo);
            }
            sa = wave_reduce_sum(sa);
            cv = wave_reduce_sum(cv);
            bvo = wave_reduce_sum(bvo);
            if (lane == 0) { consts[32] = sa; consts[33] = cv + bvo; }
        }
    }
}

// --- K5: main. lane = column n; 8 waves split d (64 each); 512-thr blocks. -
// Proven scalar inner loop (uniform A[] -> compiler s_loads), U=4 register
// double-buffer. 8192 waves total -> up to 8 waves/SIMD for latency hiding.
__launch_bounds__(512, 8)
__global__ void main_kernel(const float* __restrict__ latents,
                            const float* __restrict__ PET,
                            const float* __restrict__ A,
                            const float* __restrict__ peA,
                            const float* __restrict__ peS,
                            const float* __restrict__ peQ,
                            const float* __restrict__ consts,
                            float* __restrict__ scores,
                            float* __restrict__ vbuf, int N) {
    int b = blockIdx.y;
    int lane = threadIdx.x & 63;
    int w = threadIdx.x >> 6;
    int n = blockIdx.x * 64 + lane;
    const float scale = 22.627416997969522f;    // sqrt(512)

    int d0 = __builtin_amdgcn_readfirstlane(w * 64);   // wave-uniform
    const float* lat = latents + (size_t)b * DM * N + (size_t)d0 * N + n;
    const float* pet = PET + (size_t)d0 * N + n;

    float acc[NG];
    #pragma unroll
    for (int i = 0; i < NG; ++i) acc[i] = 0.f;
    float S1 = 0.f, S2 = 0.f, Sx = 0.f;

    const int U = 4;                 // chunk size
    const int NC = 64 / U;           // 16 chunks of 4 d each
    float xb[2][U], pb[2][U];
    #pragma unroll
    for (int u = 0; u < U; ++u) {
        xb[0][u] = lat[(size_t)u * N];
        pb[0][u] = pet[(size_t)u * N];
    }
    int cur = 0;
    for (int c = 0; c < NC; ++c) {
        int nxt = cur ^ 1;
        if (c + 1 < NC) {
            #pragma unroll
            for (int u = 0; u < U; ++u) {
                size_t dd = (size_t)((c + 1) * U + u) * N;
                xb[nxt][u] = lat[dd];
                pb[nxt][u] = pet[dd];
            }
        }
        #pragma unroll
        for (int u = 0; u < U; ++u) {
            float x = xb[cur][u], pe = pb[cur][u];
            S1 += x; S2 = fmaf(x, x, S2); Sx = fmaf(x, pe, Sx);
            int d = d0 + c * U + u;              // wave-uniform index
            #pragma unroll
            for (int q = 0; q < NG; ++q)
                acc[q] = fmaf(A[(size_t)q * DM + d], x, acc[q]);
        }
        cur = nxt;
    }

    __shared__ float red[8][NG + 3][64];
    red[w][0][lane] = S1;
    red[w][1][lane] = S2;
    red[w][2][lane] = Sx;
    #pragma unroll
    for (int i = 0; i < NG; ++i) red[w][3 + i][lane] = acc[i];
    __syncthreads();
    if (w != 0) return;

    float tot[NG + 3];
    #pragma unroll
    for (int i = 0; i < NG + 3; ++i) {
        float t = 0.f;
        #pragma unroll
        for (int k = 0; k < 8; ++k) t += red[k][i][lane];
        tot[i] = t;
    }

    float s1 = tot[0], s2 = tot[1], sx = tot[2];
    float m = (scale * s1 + peS[n]) * (1.f / DM);
    float ex2 = (scale * scale * s2 + 2.f * scale * sx + peQ[n]) * (1.f / DM);
    float rstd = rsqrtf(ex2 - m * m + 1e-5f);

    float sumAv = consts[32], CvT = consts[33];
    float v = rstd * (scale * tot[3 + NQ] + peA[(size_t)NQ * N + n] - m * sumAv) + CvT;
    vbuf[(size_t)b * N + n] = v;

    const float isd = 0.044194173824159216f;    // 1/sqrt(512)
    #pragma unroll
    for (int q = 0; q < NQ; ++q) {
        float sc = (rstd * (scale * tot[3 + q] + peA[(size_t)q * N + n] - m * consts[q])
                    + consts[16 + q]) * isd;
        scores[((size_t)b * NQ + q) * N + n] = sc;
    }
}

// --- K6: softmax, 4 rows per block (wave per row), float4 IO ---------------
__global__ void softmax_kernel(const float* __restrict__ scores,
                               const float* __restrict__ vbuf,
                               const float* __restrict__ query_mask,
                               const float* __restrict__ bo,
                               float* __restrict__ out_logits,
                               float* __restrict__ out_attn, int N) {
    int r = blockIdx.x * 4 + (threadIdx.x >> 6);   // b*NQ + q
    int b = r >> 4;
    int lane = threadIdx.x & 63;
    float4* attn_row = (float4*)(out_attn + (size_t)r * N);
    float qm = query_mask[r];
    int nv = N / 4;                     // float4 count per row
    if (qm == 0.f) {                    // fully masked row: uniform weights, wiped logits
        float u = 1.f / (float)N;
        float4 uv = make_float4(u, u, u, u);
        for (int i = lane; i < nv; i += 64) attn_row[i] = uv;
        if (lane == 0) out_logits[r] = bo[0];
        return;
    }
    const float4* srow = (const float4*)(scores + (size_t)r * N);
    float4 sv[2];
    sv[0] = srow[lane]; sv[1] = srow[64 + lane];
    float mx = fmaxf(fmaxf(fmaxf(sv[0].x, sv[0].y), fmaxf(sv[0].z, sv[0].w)),
                     fmaxf(fmaxf(sv[1].x, sv[1].y), fmaxf(sv[1].z, sv[1].w)));
    mx = wave_reduce_max(mx);
    float sum = 0.f;
    #pragma unroll
    for (int i = 0; i < 2; ++i) {
        sv[i].x = expf(sv[i].x - mx); sv[i].y = expf(sv[i].y - mx);
        sv[i].z = expf(sv[i].z - mx); sv[i].w = expf(sv[i].w - mx);
        sum += sv[i].x + sv[i].y + sv[i].z + sv[i].w;
    }
    sum = wave_reduce_sum(sum);
    float inv = 1.f / sum;
    const float4* vrow = (const float4*)(vbuf + (size_t)b * N);
    float lp = 0.f;
    #pragma unroll
    for (int i = 0; i < 2; ++i) {
        float4 vv = vrow[i * 64 + lane];
        float4 wgt;
        wgt.x = sv[i].x * inv; wgt.y = sv[i].y * inv;
        wgt.z = sv[i].z * inv; wgt.w = sv[i].w * inv;
        attn_row[i * 64 + lane] = wgt;
        lp += wgt.x * vv.x + wgt.y * vv.y + wgt.z * vv.z + wgt.w * vv.w;
    }
    lp = wave_reduce_sum(lp);
    if (lane == 0) out_logits[r] = lp + bo[0];
}

extern "C" void kernel_launch(void* const* d_in, const int* in_sizes, int n_in,
                              void* d_out, int out_size, void* d_ws, size_t ws_size,
                              hipStream_t stream) {
    const float* latents    = (const float*)d_in[0];
    const float* query_mask = (const float*)d_in[1];
    const float* query      = (const float*)d_in[2];
    const float* ln_lat_w   = (const float*)d_in[3];
    const float* ln_lat_b   = (const float*)d_in[4];
    const float* ln_q_w     = (const float*)d_in[5];
    const float* ln_q_b     = (const float*)d_in[6];
    const float* Wq         = (const float*)d_in[7];
    const float* bq         = (const float*)d_in[8];
    const float* Wk         = (const float*)d_in[9];
    const float* bk         = (const float*)d_in[10];
    const float* Wv         = (const float*)d_in[11];
    const float* bv         = (const float*)d_in[12];
    const float* Wo         = (const float*)d_in[13];
    const float* bo         = (const float*)d_in[14];

    int B = in_sizes[1] / NQ;
    int N = in_sizes[0] / (DM * B);

    float* ws = (float*)d_ws;
    size_t off = 0;
    float* PET    = ws + off; off += (size_t)DM * N;
    float* WkT    = ws + off; off += (size_t)DM * DM;
    float* WvT    = ws + off; off += (size_t)DM * DM;
    float* peS    = ws + off; off += N;
    float* peQ    = ws + off; off += N;
    float* q_ln   = ws + off; off += NQ * DM;
    float* qh     = ws + off; off += NQ * DM;
    float* qt     = ws + off; off += NQ * DM;
    float* A      = ws + off; off += NG * DM;
    float* wv     = ws + off; off += DM;
    float* peA    = ws + off; off += (size_t)NG * N;
    float* consts = ws + off; off += 64;
    float* scores = ws + off; off += (size_t)B * NQ * N;
    float* vbuf   = ws + off; off += (size_t)B * N;

    float* out_logits = (float*)d_out;
    float* out_attn   = out_logits + (size_t)B * NQ;

    k1_setup<<<257, 256, 0, stream>>>(Wk, Wv, query, ln_q_w, ln_q_b,
                                      PET, WkT, WvT, q_ln, N);
    k2_qh<<<NQ * DM / 4, 256, 0, stream>>>(q_ln, Wq, bq, qh);
    k3_qt<<<NG * DM / 4, 256, 0, stream>>>(qh, WkT, Wo, WvT, ln_lat_w, qt, A, wv);
    k4_pea<<<157, 256, 0, stream>>>(A, PET, qt, qh, wv, ln_lat_b, bk, Wo, bv,
                                    peA, peS, peQ, consts, N);
    dim3 gmain(N / 64, B);
    main_kernel<<<gmain, 512, 0, stream>>>(latents, PET, A, peA, peS, peQ, consts,
                                           scores, vbuf, N);
    softmax_kernel<<<B * NQ / 4, 256, 0, stream>>>(scores, vbuf, query_mask, bo,
                                                   out_logits, out_attn, N);
}

// Round 6
// 256.197 us; speedup vs baseline: 1.2095x; 1.1558x over previous
//
#include <hip/hip_runtime.h>
#include <math.h>

#define DM 512          // d_model
#define NQ 16           // num output queries
#define NG (NQ + 1)     // 16 score rows + 1 pooled-v row
#define NR (NG + 3)     // 20 partial rows: S1,S2,Sx,acc[0..16]

typedef __attribute__((ext_vector_type(2))) float f32x2;

__device__ __forceinline__ float wave_reduce_sum(float v) {
    #pragma unroll
    for (int off = 32; off > 0; off >>= 1) v += __shfl_xor(v, off, 64);
    return v;
}
__device__ __forceinline__ float wave_reduce_max(float v) {
    #pragma unroll
    for (int off = 32; off > 0; off >>= 1) v = fmaxf(v, __shfl_xor(v, off, 64));
    return v;
}

// --- K1: fused independent precompute --------------------------------------
// blocks 0..127   : PET[d][n] generation (8 n-tiles x 16 j-groups)
// blocks 128..255 : LDS-tiled transpose Wk->WkT, Wv->WvT
// block  256      : LayerNorm of query*scale (4 waves x 4 rows)
__global__ void k1_setup(const float* __restrict__ Wk, const float* __restrict__ Wv,
                         const float* __restrict__ query,
                         const float* __restrict__ ln_q_w, const float* __restrict__ ln_q_b,
                         float* __restrict__ PET, float* __restrict__ WkT,
                         float* __restrict__ WvT, float* __restrict__ q_ln, int N) {
    __shared__ float tile[64][65];
    int bx = blockIdx.x;
    int lane = threadIdx.x & 63;
    int w = threadIdx.x >> 6;

    if (bx < 128) {                       // --- PET ---
        int ntile = bx & 7, jg = bx >> 3;
        int n = ntile * 64 + lane;
        float p = (float)(N - 1 - n);     // reversed PE
        const float c = -logf(10000.f) / (float)DM;
        int jbase = jg * 16 + w * 4;
        #pragma unroll
        for (int u = 0; u < 4; ++u) {
            int j = jbase + u;
            float wj = expf((float)(2 * j) * c);
            float ang = p * wj;
            PET[(size_t)(2 * j) * N + n] = sinf(ang);
            PET[(size_t)(2 * j + 1) * N + n] = cosf(ang);
        }
    } else if (bx < 256) {                // --- transpose ---
        int t = bx - 128;
        const float* W = (t >> 6) ? Wv : Wk;
        float* WT = (t >> 6) ? WvT : WkT;
        int tl = t & 63;
        int te = tl >> 3, td = tl & 7;    // 8x8 tiles of 64x64
        #pragma unroll
        for (int i = 0; i < 16; ++i) {
            int el = w * 16 + i;
            tile[el][lane] = W[(size_t)(te * 64 + el) * DM + td * 64 + lane];
        }
        __syncthreads();
        #pragma unroll
        for (int i = 0; i < 16; ++i) {
            int dl = w * 16 + i;
            WT[(size_t)(td * 64 + dl) * DM + te * 64 + lane] = tile[lane][dl];
        }
    } else {                              // --- query LN ---
        const float scale = 22.627416997969522f;   // sqrt(512)
        for (int qi = 0; qi < 4; ++qi) {
            int q = w * 4 + qi;
            float vals[8], s = 0.f, s2 = 0.f;
            #pragma unroll
            for (int i = 0; i < 8; ++i) {
                float x = query[q * DM + i * 64 + lane] * scale;
                vals[i] = x; s += x; s2 += x * x;
            }
            s = wave_reduce_sum(s); s2 = wave_reduce_sum(s2);
            float m = s * (1.f / DM);
            float var = s2 * (1.f / DM) - m * m;
            float rstd = rsqrtf(var + 1e-5f);
            #pragma unroll
            for (int i = 0; i < 8; ++i) {
                int d = i * 64 + lane;
                q_ln[q * DM + d] = (vals[i] - m) * rstd * ln_q_w[d] + ln_q_b[d];
            }
        }
    }
}

// --- K2: qh[q][e] = q_ln[q] . Wq[e] + bq[e], one wave per output -----------
__global__ void k2_qh(const float* __restrict__ q_ln, const float* __restrict__ Wq,
                      const float* __restrict__ bq, float* __restrict__ qh) {
    int idx = blockIdx.x * 4 + (threadIdx.x >> 6);   // 0..8191
    int lane = threadIdx.x & 63;
    int q = idx >> 9, e = idx & 511;
    const float4* wr = (const float4*)(Wq + (size_t)e * DM);
    const float4* xr = (const float4*)(q_ln + (size_t)q * DM);
    float4 w0 = wr[lane * 2], w1 = wr[lane * 2 + 1];
    float4 x0 = xr[lane * 2], x1 = xr[lane * 2 + 1];
    float s = w0.x * x0.x + w0.y * x0.y + w0.z * x0.z + w0.w * x0.w
            + w1.x * x1.x + w1.y * x1.y + w1.z * x1.z + w1.w * x1.w;
    s = wave_reduce_sum(s);
    if (lane == 0) qh[q * DM + e] = s + bq[e];
}

// --- K3: qt[g][d] (g<16) and wv[d] (g=16) via contiguous WkT/WvT rows ------
//         A[g][d] = coeff * ln_lat_w[d]; A2 = duplicated pair for pk_fma ----
__global__ void k3_qt(const float* __restrict__ qh, const float* __restrict__ WkT,
                      const float* __restrict__ Wo, const float* __restrict__ WvT,
                      const float* __restrict__ lnw,
                      float* __restrict__ qt, float* __restrict__ A,
                      f32x2* __restrict__ A2, float* __restrict__ wvout) {
    int idx = blockIdx.x * 4 + (threadIdx.x >> 6);   // 0..8703
    int lane = threadIdx.x & 63;
    int g = idx >> 9, d = idx & 511;
    const float4* wr;
    const float4* xr;
    if (g < NQ) {
        wr = (const float4*)(WkT + (size_t)d * DM);
        xr = (const float4*)(qh + (size_t)g * DM);
    } else {
        wr = (const float4*)(WvT + (size_t)d * DM);
        xr = (const float4*)Wo;
    }
    float4 w0 = wr[lane * 2], w1 = wr[lane * 2 + 1];
    float4 x0 = xr[lane * 2], x1 = xr[lane * 2 + 1];
    float s = w0.x * x0.x + w0.y * x0.y + w0.z * x0.z + w0.w * x0.w
            + w1.x * x1.x + w1.y * x1.y + w1.z * x1.z + w1.w * x1.w;
    s = wave_reduce_sum(s);
    if (lane == 0) {
        if (g < NQ) qt[g * DM + d] = s;
        else wvout[d] = s;
        float a = s * lnw[d];
        A[g * DM + d] = a;
        f32x2 ap; ap.x = a; ap.y = a;
        A2[g * DM + d] = ap;
    }
}

// --- K4: peA rows (g<17), peS (g=17), peQ (g=18) + consts wave-tasks -------
__global__ void k4_pea(const float* __restrict__ A, const float* __restrict__ PET,
                       const float* __restrict__ qt, const float* __restrict__ qh,
                       const float* __restrict__ wv, const float* __restrict__ lnb,
                       const float* __restrict__ bk, const float* __restrict__ Wo,
                       const float* __restrict__ bv,
                       float* __restrict__ peA, float* __restrict__ peS,
                       float* __restrict__ peQ, float* __restrict__ consts, int N) {
    __shared__ float red[4][64];
    int bx = blockIdx.x;
    int lane = threadIdx.x & 63;
    int w = threadIdx.x >> 6;

    if (bx < 152) {
        int g = bx >> 3, ntile = bx & 7;
        int n = ntile * 64 + lane;
        int d0 = w * 128;
        float acc = 0.f;
        if (g < NG) {
            for (int i = 0; i < 128; ++i) {
                int d = d0 + i;
                acc = fmaf(A[(size_t)g * DM + d], PET[(size_t)d * N + n], acc);
            }
        } else if (g == NG) {
            for (int i = 0; i < 128; ++i) acc += PET[(size_t)(d0 + i) * N + n];
        } else {
            for (int i = 0; i < 128; ++i) {
                float v = PET[(size_t)(d0 + i) * N + n];
                acc = fmaf(v, v, acc);
            }
        }
        red[w][lane] = acc;
        __syncthreads();
        if (w != 0) return;
        float tot = red[0][lane] + red[1][lane] + red[2][lane] + red[3][lane];
        if (g < NG) peA[(size_t)g * N + n] = tot;
        else if (g == NG) peS[n] = tot;
        else peQ[n] = tot;
    } else {
        int t = (bx - 152) * 4 + w;       // 0..19, valid 0..16
        if (t > NQ) return;
        if (t < NQ) {
            float sa = 0.f, sc = 0.f, qb = 0.f;
            #pragma unroll
            for (int i = 0; i < 8; ++i) {
                int d = i * 64 + lane;
                sa += A[t * DM + d];
                sc = fmaf(qt[t * DM + d], lnb[d], sc);
                qb = fmaf(qh[t * DM + d], bk[d], qb);
            }
            sa = wave_reduce_sum(sa);
            sc = wave_reduce_sum(sc);
            qb = wave_reduce_sum(qb);
            if (lane == 0) { consts[t] = sa; consts[16 + t] = sc + qb; }
        } else {
            float sa = 0.f, cv = 0.f, bvo = 0.f;
            #pragma unroll
            for (int i = 0; i < 8; ++i) {
                int d = i * 64 + lane;
                sa += A[NQ * DM + d];
                cv = fmaf(wv[d], lnb[d], cv);
                bvo = fmaf(Wo[d], bv[d], bvo);
            }
            sa = wave_reduce_sum(sa);
            cv = wave_reduce_sum(cv);
            bvo = wave_reduce_sum(bvo);
            if (lane == 0) { consts[32] = sa; consts[33] = cv + bvo; }
        }
    }
}

// --- K5: main streaming. lane = 2 adjacent n (f32x2); 4 waves x 64 d;
// 2 blocks split the 512-d range (dhalf) -> partials in pbuf.
// Packed math via f32x2 (v_pk_fma_f32), A broadcast from duplicated A2.
// VGPR budget ~85 (acc 34 + buffers 32 + misc) -> no spill at 128 cap.
__launch_bounds__(256, 4)
__global__ void main2_kernel(const float* __restrict__ latents,
                             const float* __restrict__ PET,
                             const f32x2* __restrict__ A2,
                             float* __restrict__ pbuf, int N) {
    int ntiles = N >> 7;                      // 128-n tiles
    int ntile = blockIdx.x % ntiles;
    int dh = blockIdx.x / ntiles;             // 0/1: which 256-d half
    int b = blockIdx.y;
    int lane = threadIdx.x & 63;
    int w = threadIdx.x >> 6;
    int n0 = ntile * 128 + lane * 2;

    int d0 = __builtin_amdgcn_readfirstlane(dh * 256 + w * 64);
    const float* latf = latents + (size_t)b * DM * N + (size_t)d0 * N + n0;
    const float* petf = PET + (size_t)d0 * N + n0;

    f32x2 acc[NG];
    #pragma unroll
    for (int i = 0; i < NG; ++i) { acc[i].x = 0.f; acc[i].y = 0.f; }
    f32x2 S1 = {0.f, 0.f}, S2 = {0.f, 0.f}, Sx = {0.f, 0.f};

    const int U = 4;                 // d per chunk
    const int NC = 64 / U;           // 16 chunks
    f32x2 xb[2][U], pb[2][U];
    #pragma unroll
    for (int u = 0; u < U; ++u) {
        xb[0][u] = __builtin_nontemporal_load((const f32x2*)(latf + (size_t)u * N));
        pb[0][u] = *(const f32x2*)(petf + (size_t)u * N);
    }
    for (int c = 0; c < NC; c += 2) {         // explicit 2x unroll: cur/nxt static
        #pragma unroll
        for (int u = 0; u < U; ++u) {
            size_t dd = (size_t)((c + 1) * U + u) * N;
            xb[1][u] = __builtin_nontemporal_load((const f32x2*)(latf + dd));
            pb[1][u] = *(const f32x2*)(petf + dd);
        }
        #pragma unroll
        for (int u = 0; u < U; ++u) {
            f32x2 x = xb[0][u], pe = pb[0][u];
            S1 += x; S2 += x * x; Sx += x * pe;
            int d = d0 + c * U + u;
            #pragma unroll
            for (int q = 0; q < NG; ++q)
                acc[q] += A2[(size_t)q * DM + d] * x;
        }
        if (c + 2 < NC) {
            #pragma unroll
            for (int u = 0; u < U; ++u) {
                size_t dd = (size_t)((c + 2) * U + u) * N;
                xb[0][u] = __builtin_nontemporal_load((const f32x2*)(latf + dd));
                pb[0][u] = *(const f32x2*)(petf + dd);
            }
        }
        #pragma unroll
        for (int u = 0; u < U; ++u) {
            f32x2 x = xb[1][u], pe = pb[1][u];
            S1 += x; S2 += x * x; Sx += x * pe;
            int d = d0 + (c + 1) * U + u;
            #pragma unroll
            for (int q = 0; q < NG; ++q)
                acc[q] += A2[(size_t)q * DM + d] * x;
        }
    }

    __shared__ f32x2 red[4][NR][64];
    red[w][0][lane] = S1;
    red[w][1][lane] = S2;
    red[w][2][lane] = Sx;
    #pragma unroll
    for (int i = 0; i < NG; ++i) red[w][3 + i][lane] = acc[i];
    __syncthreads();
    if (w != 0) return;

    // pbuf[((dh*B + b)*NR + i)*N + n]
    float* pout = pbuf + (((size_t)dh * gridDim.y + b) * NR) * N + n0;
    #pragma unroll
    for (int i = 0; i < NR; ++i) {
        f32x2 t = red[0][i][lane] + red[1][i][lane] + red[2][i][lane] + red[3][i][lane];
        *(f32x2*)(pout + (size_t)i * N) = t;
    }
}

// --- K5b: finalize. one thread per n-pair: combine 2 d-halves, LN math,
// write vbuf + 16 score rows. ----------------------------------------------
__global__ void finalize_kernel(const float* __restrict__ pbuf,
                                const float* __restrict__ peA,
                                const float* __restrict__ peS,
                                const float* __restrict__ peQ,
                                const float* __restrict__ consts,
                                float* __restrict__ scores,
                                float* __restrict__ vbuf, int N, int B) {
    int t = blockIdx.x * 256 + threadIdx.x;
    int ppb = N >> 1;                        // n-pairs per batch
    int b = t / ppb;
    int n0 = (t - b * ppb) * 2;
    if (b >= B) return;
    const float scale = 22.627416997969522f;  // sqrt(512)

    const float* p0 = pbuf + (((size_t)0 * B + b) * NR) * N + n0;
    const float* p1 = pbuf + (((size_t)1 * B + b) * NR) * N + n0;
    f32x2 tot[NR];
    #pragma unroll
    for (int i = 0; i < NR; ++i)
        tot[i] = *(const f32x2*)(p0 + (size_t)i * N) + *(const f32x2*)(p1 + (size_t)i * N);

    f32x2 peS2 = *(const f32x2*)(peS + n0);
    f32x2 peQ2 = *(const f32x2*)(peQ + n0);
    f32x2 m = (scale * tot[0] + peS2) * (1.f / DM);
    f32x2 ex2 = (scale * scale * tot[1] + 2.f * scale * tot[2] + peQ2) * (1.f / DM);
    f32x2 rstd;
    rstd.x = rsqrtf(ex2.x - m.x * m.x + 1e-5f);
    rstd.y = rsqrtf(ex2.y - m.y * m.y + 1e-5f);

    float sumAv = consts[32], CvT = consts[33];
    f32x2 peAv = *(const f32x2*)(peA + (size_t)NQ * N + n0);
    f32x2 v = rstd * (scale * tot[3 + NQ] + peAv - m * sumAv) + CvT;
    *(f32x2*)(vbuf + (size_t)b * N + n0) = v;

    const float isd = 0.044194173824159216f;  // 1/sqrt(512)
    #pragma unroll
    for (int q = 0; q < NQ; ++q) {
        f32x2 peAq = *(const f32x2*)(peA + (size_t)q * N + n0);
        f32x2 sc = (rstd * (scale * tot[3 + q] + peAq - m * consts[q])
                    + consts[16 + q]) * isd;
        *(f32x2*)(scores + ((size_t)b * NQ + q) * N + n0) = sc;
    }
}

// --- K6: softmax, 4 rows per block (wave per row), float4 IO ---------------
__global__ void softmax_kernel(const float* __restrict__ scores,
                               const float* __restrict__ vbuf,
                               const float* __restrict__ query_mask,
                               const float* __restrict__ bo,
                               float* __restrict__ out_logits,
                               float* __restrict__ out_attn, int N) {
    int r = blockIdx.x * 4 + (threadIdx.x >> 6);   // b*NQ + q
    int b = r >> 4;
    int lane = threadIdx.x & 63;
    float4* attn_row = (float4*)(out_attn + (size_t)r * N);
    float qm = query_mask[r];
    int nv = N / 4;                     // float4 count per row
    if (qm == 0.f) {                    // fully masked row: uniform weights, wiped logits
        float u = 1.f / (float)N;
        float4 uv = make_float4(u, u, u, u);
        for (int i = lane; i < nv; i += 64) attn_row[i] = uv;
        if (lane == 0) out_logits[r] = bo[0];
        return;
    }
    const float4* srow = (const float4*)(scores + (size_t)r * N);
    float4 sv[2];
    sv[0] = srow[lane]; sv[1] = srow[64 + lane];
    float mx = fmaxf(fmaxf(fmaxf(sv[0].x, sv[0].y), fmaxf(sv[0].z, sv[0].w)),
                     fmaxf(fmaxf(sv[1].x, sv[1].y), fmaxf(sv[1].z, sv[1].w)));
    mx = wave_reduce_max(mx);
    float sum = 0.f;
    #pragma unroll
    for (int i = 0; i < 2; ++i) {
        sv[i].x = expf(sv[i].x - mx); sv[i].y = expf(sv[i].y - mx);
        sv[i].z = expf(sv[i].z - mx); sv[i].w = expf(sv[i].w - mx);
        sum += sv[i].x + sv[i].y + sv[i].z + sv[i].w;
    }
    sum = wave_reduce_sum(sum);
    float inv = 1.f / sum;
    const float4* vrow = (const float4*)(vbuf + (size_t)b * N);
    float lp = 0.f;
    #pragma unroll
    for (int i = 0; i < 2; ++i) {
        float4 vv = vrow[i * 64 + lane];
        float4 wgt;
        wgt.x = sv[i].x * inv; wgt.y = sv[i].y * inv;
        wgt.z = sv[i].z * inv; wgt.w = sv[i].w * inv;
        attn_row[i * 64 + lane] = wgt;
        lp += wgt.x * vv.x + wgt.y * vv.y + wgt.z * vv.z + wgt.w * vv.w;
    }
    lp = wave_reduce_sum(lp);
    if (lane == 0) out_logits[r] = lp + bo[0];
}

extern "C" void kernel_launch(void* const* d_in, const int* in_sizes, int n_in,
                              void* d_out, int out_size, void* d_ws, size_t ws_size,
                              hipStream_t stream) {
    const float* latents    = (const float*)d_in[0];
    const float* query_mask = (const float*)d_in[1];
    const float* query      = (const float*)d_in[2];
    const float* ln_lat_w   = (const float*)d_in[3];
    const float* ln_lat_b   = (const float*)d_in[4];
    const float* ln_q_w     = (const float*)d_in[5];
    const float* ln_q_b     = (const float*)d_in[6];
    const float* Wq         = (const float*)d_in[7];
    const float* bq         = (const float*)d_in[8];
    const float* Wk         = (const float*)d_in[9];
    const float* bk         = (const float*)d_in[10];
    const float* Wv         = (const float*)d_in[11];
    const float* bv         = (const float*)d_in[12];
    const float* Wo         = (const float*)d_in[13];
    const float* bo         = (const float*)d_in[14];

    int B = in_sizes[1] / NQ;
    int N = in_sizes[0] / (DM * B);

    float* ws = (float*)d_ws;
    size_t off = 0;
    float* PET    = ws + off; off += (size_t)DM * N;
    float* WkT    = ws + off; off += (size_t)DM * DM;
    float* WvT    = ws + off; off += (size_t)DM * DM;
    float* peS    = ws + off; off += N;
    float* peQ    = ws + off; off += N;
    float* q_ln   = ws + off; off += NQ * DM;
    float* qh     = ws + off; off += NQ * DM;
    float* qt     = ws + off; off += NQ * DM;
    float* A      = ws + off; off += NG * DM;
    float* A2     = ws + off; off += (size_t)NG * DM * 2;
    float* wv     = ws + off; off += DM;
    float* peA    = ws + off; off += (size_t)NG * N;
    float* consts = ws + off; off += 64;
    float* scores = ws + off; off += (size_t)B * NQ * N;
    float* vbuf   = ws + off; off += (size_t)B * N;
    float* pbuf   = ws + off; off += (size_t)2 * B * NR * N;

    float* out_logits = (float*)d_out;
    float* out_attn   = out_logits + (size_t)B * NQ;

    k1_setup<<<257, 256, 0, stream>>>(Wk, Wv, query, ln_q_w, ln_q_b,
                                      PET, WkT, WvT, q_ln, N);
    k2_qh<<<NQ * DM / 4, 256, 0, stream>>>(q_ln, Wq, bq, qh);
    k3_qt<<<NG * DM / 4, 256, 0, stream>>>(qh, WkT, Wo, WvT, ln_lat_w,
                                           qt, A, (f32x2*)A2, wv);
    k4_pea<<<157, 256, 0, stream>>>(A, PET, qt, qh, wv, ln_lat_b, bk, Wo, bv,
                                    peA, peS, peQ, consts, N);
    dim3 gmain((N >> 7) * 2, B);
    main2_kernel<<<gmain, 256, 0, stream>>>(latents, PET, (const f32x2*)A2,
                                            pbuf, N);
    int fin_threads = B * (N / 2);
    finalize_kernel<<<(fin_threads + 255) / 256, 256, 0, stream>>>(
        pbuf, peA, peS, peQ, consts, scores, vbuf, N, B);
    softmax_kernel<<<B * NQ / 4, 256, 0, stream>>>(scores, vbuf, query_mask, bo,
                                                   out_logits, out_attn, N);
}